// Round 8
// baseline (377.492 us; speedup 1.0000x reference)
//
#include <hip/hip_runtime.h>
#include <stdint.h>

#define B_DIM 4
#define L_DIM 512
#define D_DIM 768
#define S_DIM 4096
#define DFF_DIM 3072
#define M_DIM (B_DIM * S_DIM)   // 16384

typedef unsigned short ushort_t;
typedef __attribute__((ext_vector_type(8))) short short8;
typedef __attribute__((ext_vector_type(4))) float floatx4;

// round-to-nearest-even fp32 -> bf16 bits
__device__ __forceinline__ ushort_t f2bf(float x) {
  unsigned int u = __float_as_uint(x);
  u += 0x7FFFu + ((u >> 16) & 1u);
  return (ushort_t)(u >> 16);
}

// async 16B global->LDS (wave-uniform base + lane*16 layout required)
__device__ __forceinline__ void load_lds16(const ushort_t* g, ushort_t* lds) {
  __builtin_amdgcn_global_load_lds(
      (const __attribute__((address_space(1))) unsigned int*)g,
      (__attribute__((address_space(3))) unsigned int*)lds, 16, 0, 0);
}

// ---------------------------------------------------------------------------
// Fused prep: W1 transpose | W2 transpose | span gather+mean, one launch.
// ---------------------------------------------------------------------------
__device__ __forceinline__ void transpose_body(const float* __restrict__ in,
                                               ushort_t* __restrict__ out,
                                               int K, int N, int kb, int nb) {
  __shared__ float tile[32][33];
  const int k0 = kb * 32;
  const int n0 = nb * 32;
  const int tx = threadIdx.x & 31;
  const int ty = threadIdx.x >> 5;  // 0..7
#pragma unroll
  for (int r = 0; r < 32; r += 8)
    tile[ty + r][tx] = in[(long)(k0 + ty + r) * N + n0 + tx];
  __syncthreads();
#pragma unroll
  for (int r = 0; r < 32; r += 8)
    out[(long)(n0 + ty + r) * K + k0 + tx] = f2bf(tile[tx][ty + r]);
}

__device__ __forceinline__ void span_body(const float* __restrict__ h,
                                          const int* __restrict__ span_idx,
                                          ushort_t* __restrict__ A, int blk) {
  const int wave = threadIdx.x >> 6;
  const int lane = threadIdx.x & 63;
  const int span = blk * 4 + wave;  // 0..M-1
  const int b = span >> 12;         // span / S_DIM
  const int start = span_idx[span * 2 + 0];
  const int end   = span_idx[span * 2 + 1];
  const float inv = 1.0f / (float)(end - start + 1);
  const float* hb = h + ((long)b * L_DIM + start) * D_DIM + lane;
  float a[12];
#pragma unroll
  for (int c = 0; c < 12; ++c) a[c] = 0.0f;
  for (int p = start; p <= end; ++p) {
#pragma unroll
    for (int c = 0; c < 12; ++c) a[c] += hb[c * 64];
    hb += D_DIM;
  }
  ushort_t* o = A + (long)span * D_DIM + lane;
#pragma unroll
  for (int c = 0; c < 12; ++c) o[c * 64] = f2bf(a[c] * inv);
}

__global__ __launch_bounds__(256)
void prep(const float* __restrict__ W1, ushort_t* __restrict__ W1T,
          const float* __restrict__ W2, ushort_t* __restrict__ W2T,
          const float* __restrict__ h, const int* __restrict__ span_idx,
          ushort_t* __restrict__ A) {
  const int blk = blockIdx.x;
  if (blk < 2304) {
    transpose_body(W1, W1T, D_DIM, DFF_DIM, blk % 24, blk / 24);
  } else if (blk < 4608) {
    const int b = blk - 2304;
    transpose_body(W2, W2T, DFF_DIM, D_DIM, b % 96, b / 96);
  } else {
    span_body(h, span_idx, A, blk - 4608);
  }
}

// ---------------------------------------------------------------------------
// bf16 GEMM: C[M][N] = A[M][K] * Bt[N][K]^T (+bias epilogue)
// 256x256 block tile, BK=32, 256 threads = 4 waves, each wave a 128x128
// sub-tile via 8x8 grid of mfma 16x16x32 (64 independent MFMAs/iter).
//
// Rationale (R1-R7 post-mortems): the 128x128/4-wave structure is
// LDS-pipe-bound: 48 KB LDS traffic per block-iter vs ~78 cyc/SIMD of MFMA
// (5:1) == the pinned ~25% MfmaUtil, invariant to barriers/buffering/
// occupancy. 8x8 fragments halve BOTH LDS bytes/FLOP ((8+8)/64 vs (4+4)/16)
// and DMA bytes/FLOP ((BM+BN)/(BM*BN)). Cost: 256 acc VGPRs -> 1 wave/SIMD,
// which R7 showed is not the limiter (MFMAs within an iter are independent).
// Double-buffered LDS (64 KB), one barrier per iteration.
// MODE 0: out = relu(acc + bias[col]) -> bf16   (GEMM1 -> Hmid)
// MODE 1: out = acc + bias[col]       -> fp32   (GEMM2 -> final)
// M, N multiples of 256; K multiple of 32.
// ---------------------------------------------------------------------------
template <int MODE>
__global__ __launch_bounds__(256, 1)
void gemm_bt(const ushort_t* __restrict__ A, const ushort_t* __restrict__ Bt,
             const float* __restrict__ bias, void* __restrict__ Cv,
             int M, int N, int K) {
  __shared__ ushort_t As[2][256 * 32];
  __shared__ ushort_t Bs[2][256 * 32];

  const int tid  = threadIdx.x;
  const int lane = tid & 63;
  const int wave = tid >> 6;
  const int l16  = lane & 15;
  const int quad = lane >> 4;

  const int bm = blockIdx.x;
  const int bn = blockIdx.y;

  const int wm = (wave & 1) * 128;
  const int wn = (wave >> 1) * 128;

  floatx4 acc[8][8];
#pragma unroll
  for (int i = 0; i < 8; ++i)
#pragma unroll
    for (int j = 0; j < 8; ++j)
      acc[i][j] = (floatx4)0.0f;

  // staging: 1024 16-B segments per operand tile (256 rows x 4 k-chunks).
  // Thread t covers segs t, t+256, t+512, t+768 -> rows (t>>2)+{0,64,128,192},
  // chunk t&3. LDS elem offset of seg s is s*8.
  const ushort_t* gA0 = A + (long)(bm * 256 + (tid >> 2)) * K + (tid & 3) * 8;
  const ushort_t* gB0 = Bt + (long)(bn * 256 + (tid >> 2)) * K + (tid & 3) * 8;
  const long rstep = (long)64 * K;  // +64 rows, same chunk

  const int nk = K >> 5;  // K/32 iterations

  // prologue: tile 0 -> buffer 0
#pragma unroll
  for (int r = 0; r < 4; ++r) {
    load_lds16(gA0 + r * rstep, &As[0][0] + tid * 8 + r * 2048);
    load_lds16(gB0 + r * rstep, &Bs[0][0] + tid * 8 + r * 2048);
  }

  for (int k = 0; k < nk; ++k) {
    const int cur = k & 1;
    const int nxt = cur ^ 1;
    __syncthreads();  // drains DMA of tile k (issued one iteration ago)

    if (k + 1 < nk) {  // prefetch tile k+1 into the other buffer
      const int off = (k + 1) * 32;
#pragma unroll
      for (int r = 0; r < 4; ++r) {
        load_lds16(gA0 + r * rstep + off, &As[nxt][0] + tid * 8 + r * 2048);
        load_lds16(gB0 + r * rstep + off, &Bs[nxt][0] + tid * 8 + r * 2048);
      }
    }

    short8 af[8], bf[8];
#pragma unroll
    for (int i = 0; i < 8; ++i)
      af[i] = *(const short8*)(&As[cur][0] + (wm + i * 16 + l16) * 32 + quad * 8);
#pragma unroll
    for (int j = 0; j < 8; ++j)
      bf[j] = *(const short8*)(&Bs[cur][0] + (wn + j * 16 + l16) * 32 + quad * 8);
#pragma unroll
    for (int i = 0; i < 8; ++i)
#pragma unroll
      for (int j = 0; j < 8; ++j)
        acc[i][j] = __builtin_amdgcn_mfma_f32_16x16x32_bf16(af[i], bf[j], acc[i][j], 0, 0, 0);
  }

  // epilogue: C/D layout col = lane&15, row = quad*4 + r
#pragma unroll
  for (int i = 0; i < 8; ++i) {
#pragma unroll
    for (int j = 0; j < 8; ++j) {
      const int col = bn * 256 + wn + j * 16 + l16;
      const float bv = bias[col];
      const int row0 = bm * 256 + wm + i * 16 + quad * 4;
#pragma unroll
      for (int r = 0; r < 4; ++r) {
        float v = acc[i][j][r] + bv;
        if (MODE == 0) {
          v = v > 0.0f ? v : 0.0f;
          ((ushort_t*)Cv)[(long)(row0 + r) * N + col] = f2bf(v);
        } else {
          ((float*)Cv)[(long)(row0 + r) * N + col] = v;
        }
      }
    }
  }
}

extern "C" void kernel_launch(void* const* d_in, const int* in_sizes, int n_in,
                              void* d_out, int out_size, void* d_ws, size_t ws_size,
                              hipStream_t stream) {
  const float* h        = (const float*)d_in[0];
  const int*   span_idx = (const int*)d_in[1];
  const float* W1       = (const float*)d_in[2];
  const float* b1       = (const float*)d_in[3];
  const float* W2       = (const float*)d_in[4];
  const float* b2       = (const float*)d_in[5];
  float* out = (float*)d_out;

  // workspace layout (bf16 elements): A | W1T | W2T | Hmid
  ushort_t* A   = (ushort_t*)d_ws;
  ushort_t* W1T = A + (size_t)M_DIM * D_DIM;
  ushort_t* W2T = W1T + (size_t)DFF_DIM * D_DIM;
  ushort_t* Hm  = W2T + (size_t)D_DIM * DFF_DIM;

  // fused prep: both weight transposes + span gather in one launch
  prep<<<2304 + 2304 + M_DIM / 4, 256, 0, stream>>>(W1, W1T, W2, W2T, h, span_idx, A);

  // GEMM1: A (M x D) * W1 (D x DFF) + b1, relu -> Hmid bf16 (M x DFF)
  // 256x256 tile: 64 x 12 = 768 blocks.
  gemm_bt<0><<<dim3(M_DIM / 256, DFF_DIM / 256), 256, 0, stream>>>(
      A, W1T, b1, Hm, M_DIM, DFF_DIM, D_DIM);

  // GEMM2: Hmid (M x DFF) * W2 (DFF x D) + b2 -> out fp32 (M x D)
  // 256x256 tile: 64 x 3 = 192 blocks.
  gemm_bt<1><<<dim3(M_DIM / 256, D_DIM / 256), 256, 0, stream>>>(
      Hm, W2T, b2, out, M_DIM, D_DIM, DFF_DIM);
}

// Round 9
// 286.739 us; speedup vs baseline: 1.3165x; 1.3165x over previous
//
#include <hip/hip_runtime.h>
#include <stdint.h>

#define B_DIM 4
#define L_DIM 512
#define D_DIM 768
#define S_DIM 4096
#define DFF_DIM 3072
#define M_DIM (B_DIM * S_DIM)   // 16384
#define HROWS (B_DIM * L_DIM)   // 2048 distinct h rows

typedef unsigned short ushort_t;
typedef __attribute__((ext_vector_type(8))) short short8;
typedef __attribute__((ext_vector_type(8))) ushort_t ushort8;
typedef __attribute__((ext_vector_type(4))) float floatx4;

// round-to-nearest-even fp32 -> bf16 bits
__device__ __forceinline__ ushort_t f2bf(float x) {
  unsigned int u = __float_as_uint(x);
  u += 0x7FFFu + ((u >> 16) & 1u);
  return (ushort_t)(u >> 16);
}

// async 16B global->LDS (wave-uniform base + lane*16 layout required)
__device__ __forceinline__ void load_lds16(const ushort_t* g, ushort_t* lds) {
  __builtin_amdgcn_global_load_lds(
      (const __attribute__((address_space(1))) unsigned int*)g,
      (__attribute__((address_space(3))) unsigned int*)lds, 16, 0, 0);
}

// ---------------------------------------------------------------------------
// Fused prep: W1 transpose | W2 transpose | h fp32->bf16 cast, one launch.
// blocks [0,2304): W1 (768x3072) -> W1T (3072x768) bf16
// blocks [2304,4608): W2 (3072x768) -> W2T (768x3072) bf16
// blocks [4608,5376): flat cast h -> Hbf (2048x768 bf16), 2048 elems/block
// ---------------------------------------------------------------------------
__device__ __forceinline__ void transpose_body(const float* __restrict__ in,
                                               ushort_t* __restrict__ out,
                                               int K, int N, int kb, int nb) {
  __shared__ float tile[32][33];
  const int k0 = kb * 32;
  const int n0 = nb * 32;
  const int tx = threadIdx.x & 31;
  const int ty = threadIdx.x >> 5;  // 0..7
#pragma unroll
  for (int r = 0; r < 32; r += 8)
    tile[ty + r][tx] = in[(long)(k0 + ty + r) * N + n0 + tx];
  __syncthreads();
#pragma unroll
  for (int r = 0; r < 32; r += 8)
    out[(long)(n0 + ty + r) * K + k0 + tx] = f2bf(tile[tx][ty + r]);
}

__global__ __launch_bounds__(256)
void prep(const float* __restrict__ W1, ushort_t* __restrict__ W1T,
          const float* __restrict__ W2, ushort_t* __restrict__ W2T,
          const float* __restrict__ h, ushort_t* __restrict__ Hbf) {
  const int blk = blockIdx.x;
  if (blk < 2304) {
    transpose_body(W1, W1T, D_DIM, DFF_DIM, blk % 24, blk / 24);
  } else if (blk < 4608) {
    const int b = blk - 2304;
    transpose_body(W2, W2T, DFF_DIM, D_DIM, b % 96, b / 96);
  } else {
    const long base = (long)(blk - 4608) * 2048 + threadIdx.x * 8;
    const float4 v0 = *(const float4*)(h + base);
    const float4 v1 = *(const float4*)(h + base + 4);
    ushort8 o;
    o[0] = f2bf(v0.x); o[1] = f2bf(v0.y); o[2] = f2bf(v0.z); o[3] = f2bf(v0.w);
    o[4] = f2bf(v1.x); o[5] = f2bf(v1.y); o[6] = f2bf(v1.z); o[7] = f2bf(v1.w);
    *(ushort8*)(Hbf + base) = o;
  }
}

// ---------------------------------------------------------------------------
// Prefix scan over L: P[b][0][c]=0; P[b][l+1][c] = P[b][l][c] + HW1[b*512+l][c]
// grid = 12 blocks (4 batches x 3 col-chunks of 1024), 256 threads x float4.
// ---------------------------------------------------------------------------
__global__ __launch_bounds__(256)
void scan_l(const float* __restrict__ HW1, float* __restrict__ P) {
  const int b  = blockIdx.x / 3;
  const int cc = blockIdx.x % 3;
  const int col = cc * 1024 + threadIdx.x * 4;
  const float* src = HW1 + (long)b * L_DIM * DFF_DIM + col;
  float* dst = P + (long)b * (L_DIM + 1) * DFF_DIM + col;
  float4 v = make_float4(0.f, 0.f, 0.f, 0.f);
  *(float4*)dst = v;
  for (int l = 0; l < L_DIM; ++l) {
    const float4 x = *(const float4*)(src + (long)l * DFF_DIM);
    v.x += x.x; v.y += x.y; v.z += x.z; v.w += x.w;
    *(float4*)(dst + (long)(l + 1) * DFF_DIM) = v;
  }
}

// ---------------------------------------------------------------------------
// Gather: Hmid[span][k] = relu((P[b][end+1][k] - P[b][start][k])*inv + b1[k])
// unit = span*384 + col8; thread per unit; 24576 blocks x 256.
// ---------------------------------------------------------------------------
__global__ __launch_bounds__(256)
void gather_spans(const float* __restrict__ P, const int* __restrict__ span_idx,
                  const float* __restrict__ b1, ushort_t* __restrict__ Hmid) {
  const unsigned unit = blockIdx.x * 256 + threadIdx.x;
  const unsigned span = unit / 384;
  const unsigned c8   = unit % 384;
  const int b     = span >> 12;
  const int start = span_idx[span * 2 + 0];
  const int end   = span_idx[span * 2 + 1];
  const float inv = 1.0f / (float)(end - start + 1);
  const float* pe = P + ((long)b * (L_DIM + 1) + end + 1) * DFF_DIM + c8 * 8;
  const float* ps = P + ((long)b * (L_DIM + 1) + start) * DFF_DIM + c8 * 8;
  const float4 e0 = *(const float4*)(pe);
  const float4 e1 = *(const float4*)(pe + 4);
  const float4 s0 = *(const float4*)(ps);
  const float4 s1 = *(const float4*)(ps + 4);
  const float4 g0 = *(const float4*)(b1 + c8 * 8);
  const float4 g1 = *(const float4*)(b1 + c8 * 8 + 4);
  float v[8];
  v[0] = (e0.x - s0.x) * inv + g0.x;
  v[1] = (e0.y - s0.y) * inv + g0.y;
  v[2] = (e0.z - s0.z) * inv + g0.z;
  v[3] = (e0.w - s0.w) * inv + g0.w;
  v[4] = (e1.x - s1.x) * inv + g1.x;
  v[5] = (e1.y - s1.y) * inv + g1.y;
  v[6] = (e1.z - s1.z) * inv + g1.z;
  v[7] = (e1.w - s1.w) * inv + g1.w;
  ushort8 o;
#pragma unroll
  for (int i = 0; i < 8; ++i) o[i] = f2bf(v[i] > 0.f ? v[i] : 0.f);
  *(ushort8*)(Hmid + (long)span * DFF_DIM + c8 * 8) = o;
}

// ---------------------------------------------------------------------------
// bf16 GEMM (R4 config — best measured of the family): C = A * Bt^T
// 128x128 tile, BK=32, 4 waves x (4x4 of 16x16x32), double-buffered LDS
// via global_load_lds, one barrier per iteration.
// MODE 0: relu(acc + bias[col]) -> bf16
// MODE 1: acc + bias[col]       -> fp32
// MODE 2: acc                   -> fp32 (no bias)
// ---------------------------------------------------------------------------
template <int MODE>
__global__ __launch_bounds__(256)
void gemm_bt(const ushort_t* __restrict__ A, const ushort_t* __restrict__ Bt,
             const float* __restrict__ bias, void* __restrict__ Cv,
             int M, int N, int K) {
  __shared__ ushort_t As[2][128 * 32];
  __shared__ ushort_t Bs[2][128 * 32];

  const int tid  = threadIdx.x;
  const int lane = tid & 63;
  const int wave = tid >> 6;
  const int l16  = lane & 15;
  const int quad = lane >> 4;

  const int bm = blockIdx.x;
  const int bn = blockIdx.y;

  const int wm = (wave & 1) * 64;
  const int wn = (wave >> 1) * 64;

  floatx4 acc[4][4];
#pragma unroll
  for (int i = 0; i < 4; ++i)
#pragma unroll
    for (int j = 0; j < 4; ++j)
      acc[i][j] = (floatx4)0.0f;

  // staging: 512 16-B segments per tile; seg s -> row s>>2, chunk s&3;
  // LDS elem offset of seg s is s*8. Thread t covers segs t and t+256.
  const int s0 = tid, s1 = tid + 256;
  const ushort_t* gA0 = A + (long)(bm * 128 + (s0 >> 2)) * K + (s0 & 3) * 8;
  const ushort_t* gA1 = A + (long)(bm * 128 + (s1 >> 2)) * K + (s1 & 3) * 8;
  const ushort_t* gB0 = Bt + (long)(bn * 128 + (s0 >> 2)) * K + (s0 & 3) * 8;
  const ushort_t* gB1 = Bt + (long)(bn * 128 + (s1 >> 2)) * K + (s1 & 3) * 8;

  const int nk = K >> 5;

  // prologue: tile 0 -> buffer 0
  load_lds16(gA0, &As[0][0] + s0 * 8);
  load_lds16(gA1, &As[0][0] + s1 * 8);
  load_lds16(gB0, &Bs[0][0] + s0 * 8);
  load_lds16(gB1, &Bs[0][0] + s1 * 8);

  for (int k = 0; k < nk; ++k) {
    const int cur = k & 1;
    const int nxt = cur ^ 1;
    __syncthreads();  // drains DMA of tile k (issued one iteration ago)

    if (k + 1 < nk) {
      const int off = (k + 1) * 32;
      load_lds16(gA0 + off, &As[nxt][0] + s0 * 8);
      load_lds16(gA1 + off, &As[nxt][0] + s1 * 8);
      load_lds16(gB0 + off, &Bs[nxt][0] + s0 * 8);
      load_lds16(gB1 + off, &Bs[nxt][0] + s1 * 8);
    }

    short8 af[4], bf[4];
#pragma unroll
    for (int i = 0; i < 4; ++i)
      af[i] = *(const short8*)(&As[cur][0] + (wm + i * 16 + l16) * 32 + quad * 8);
#pragma unroll
    for (int j = 0; j < 4; ++j)
      bf[j] = *(const short8*)(&Bs[cur][0] + (wn + j * 16 + l16) * 32 + quad * 8);
#pragma unroll
    for (int i = 0; i < 4; ++i)
#pragma unroll
      for (int j = 0; j < 4; ++j)
        acc[i][j] = __builtin_amdgcn_mfma_f32_16x16x32_bf16(af[i], bf[j], acc[i][j], 0, 0, 0);
  }

  // epilogue: C/D layout col = lane&15, row = quad*4 + r
#pragma unroll
  for (int i = 0; i < 4; ++i) {
#pragma unroll
    for (int j = 0; j < 4; ++j) {
      const int col = bn * 128 + wn + j * 16 + l16;
      const float bv = (MODE == 2) ? 0.0f : bias[col];
      const int row0 = bm * 128 + wm + i * 16 + quad * 4;
#pragma unroll
      for (int r = 0; r < 4; ++r) {
        float v = acc[i][j][r] + bv;
        if (MODE == 0) {
          v = v > 0.0f ? v : 0.0f;
          ((ushort_t*)Cv)[(long)(row0 + r) * N + col] = f2bf(v);
        } else {
          ((float*)Cv)[(long)(row0 + r) * N + col] = v;
        }
      }
    }
  }
}

extern "C" void kernel_launch(void* const* d_in, const int* in_sizes, int n_in,
                              void* d_out, int out_size, void* d_ws, size_t ws_size,
                              hipStream_t stream) {
  const float* h        = (const float*)d_in[0];
  const int*   span_idx = (const int*)d_in[1];
  const float* W1       = (const float*)d_in[2];
  const float* b1       = (const float*)d_in[3];
  const float* W2       = (const float*)d_in[4];
  const float* b2       = (const float*)d_in[5];
  float* out = (float*)d_out;

  // workspace layout (bytes):
  //   [0)            W2T  (768x3072 bf16, 4.72 MB)
  //   [4718592)      P    (4x513x3072 fp32, 25.2 MB)
  //   [29933568)     Hmid region (16384x3072 bf16, 100.7 MB); inside it:
  //       +0         HW1  (2048x3072 fp32, 25.2 MB)  [dead after scan]
  //       +32MB      W1T  (3072x768 bf16, 4.72 MB)   [dead after GEMM-A]
  //       +40MB      Hbf  (2048x768 bf16, 3.1 MB)    [dead after GEMM-A]
  // gather overwrites the whole region with Hmid AFTER GEMM-A and scan.
  char* ws = (char*)d_ws;
  ushort_t* W2T  = (ushort_t*)ws;
  float*    P    = (float*)(ws + 4718592);
  char*     reg  = ws + 29933568;
  ushort_t* Hmid = (ushort_t*)reg;
  float*    HW1  = (float*)reg;
  ushort_t* W1T  = (ushort_t*)(reg + 33554432);
  ushort_t* Hbf  = (ushort_t*)(reg + 41943040);

  // prep: W1T, W2T transposes + h->bf16 cast
  prep<<<2304 + 2304 + 768, 256, 0, stream>>>(W1, W1T, W2, W2T, h, Hbf);

  // GEMM-A: Hbf (2048 x 768) * W1 -> HW1 fp32 (2048 x 3072). 9.7 GF.
  gemm_bt<2><<<dim3(HROWS / 128, DFF_DIM / 128), 256, 0, stream>>>(
      Hbf, W1T, nullptr, HW1, HROWS, DFF_DIM, D_DIM);

  // prefix scan over L per (batch, col)
  scan_l<<<12, 256, 0, stream>>>(HW1, P);

  // gather: span means from P, +b1, relu -> Hmid bf16 (16384 x 3072)
  gather_spans<<<(M_DIM * (DFF_DIM / 8)) / 256, 256, 0, stream>>>(
      P, span_idx, b1, Hmid);

  // GEMM2: Hmid (M x DFF) * W2 + b2 -> out fp32 (M x D)
  gemm_bt<1><<<dim3(M_DIM / 128, D_DIM / 128), 256, 0, stream>>>(
      Hmid, W2T, b2, out, M_DIM, D_DIM, DFF_DIM);
}